// Round 1
// baseline (598.915 us; speedup 1.0000x reference)
//
#include <hip/hip_runtime.h>

// FlowWarp: 6 pyramid levels. Per level i:
//   warped = bilinear_warp(xp, +fl)   (dense_image_warp with flow=-fl)
//   x = concat([xc(64), warped(64), fl(2)])  -> 130 ch
//   out[f] = sum_c x[c]*dw[c]*pw[c][f] + bias[f]   (F=64)
// Inputs per level (dict order): xc, xp, fl, dw, pw, bias  -> d_in[6*i + k]
// Output: 6 outputs concatenated flat, fp32.

struct LevelArgs {
  const float* __restrict__ xc;
  const float* __restrict__ xp;
  const float* __restrict__ fl;
  const float* __restrict__ dw;
  const float* __restrict__ pw;
  const float* __restrict__ bias;
  float* __restrict__ out;
  int H, W, npix, block_start;
};

struct KArgs { LevelArgs lv[6]; };

__global__ __launch_bounds__(256, 4) void flowwarp_kernel(KArgs ka) {
  const int b = (int)blockIdx.x;
  int Lr = 0;
#pragma unroll
  for (int i = 1; i < 6; ++i) Lr = (b >= ka.lv[i].block_start) ? i : Lr;
  const int L = __builtin_amdgcn_readfirstlane(Lr);  // wave-uniform level
  const LevelArgs A = ka.lv[L];

  const int p = (b - A.block_start) * 256 + (int)threadIdx.x;
  if (p >= A.npix) return;

  const int W = A.W, H = A.H;
  const int x = p % W;
  const int t = p / W;
  const int y = t % H;
  const int n = t / H;

  // ---- warp coordinates (matches tfa dense_image_warp with flow=-fl) ----
  const float fl0 = A.fl[2 * (size_t)p];
  const float fl1 = A.fl[2 * (size_t)p + 1];
  const float qy = (float)y + fl0;   // gy - (-fl_y)
  const float qx = (float)x + fl1;
  const float fy = fminf(fmaxf(floorf(qy), 0.0f), (float)(H - 2));
  const float fx = fminf(fmaxf(floorf(qx), 0.0f), (float)(W - 2));
  const int y0 = (int)fy, x0 = (int)fx;
  const float ay = fminf(fmaxf(qy - fy, 0.0f), 1.0f);
  const float ax = fminf(fmaxf(qx - fx, 0.0f), 1.0f);

  // ---- accumulators: init with bias + flow-channel (c=128,129) terms ----
  float acc[64];
  {
    const float s0 = fl0 * A.dw[128];
    const float s1 = fl1 * A.dw[129];
    const float* __restrict__ pr0 = A.pw + 128 * 64;
    const float* __restrict__ pr1 = A.pw + 129 * 64;
#pragma unroll
    for (int f = 0; f < 64; ++f)
      acc[f] = fmaf(s0, pr0[f], fmaf(s1, pr1[f], A.bias[f]));
  }

  // ---- current-frame channels c = 0..63 ----
  {
    const float4* __restrict__ xc4 = (const float4*)(A.xc + (size_t)p * 64);
    for (int c4 = 0; c4 < 16; ++c4) {   // rolled: keeps code size sane
      const float4 xv = xc4[c4];
      const float v[4] = {xv.x, xv.y, xv.z, xv.w};
#pragma unroll
      for (int j = 0; j < 4; ++j) {
        const int c = c4 * 4 + j;
        const float vv = v[j] * A.dw[c];          // dw uniform -> s_load
        const float* __restrict__ pwr = A.pw + (size_t)c * 64;  // uniform row
#pragma unroll
        for (int f = 0; f < 64; ++f) acc[f] = fmaf(vv, pwr[f], acc[f]);
      }
    }
  }

  // ---- warped channels c = 64..127 ----
  {
    const size_t cbase = ((size_t)(n * H + y0) * W + x0) * 64;
    const float* __restrict__ tlp = A.xp + cbase;
    const float4* __restrict__ tl4 = (const float4*)tlp;
    const float4* __restrict__ tr4 = (const float4*)(tlp + 64);
    const float4* __restrict__ bl4 = (const float4*)(tlp + (size_t)W * 64);
    const float4* __restrict__ br4 = (const float4*)(tlp + (size_t)W * 64 + 64);
    for (int c4 = 0; c4 < 16; ++c4) {
      const float4 a = tl4[c4], bq = tr4[c4], cl = bl4[c4], dr = br4[c4];
      float wv[4];
      {
        float top, bot;
        top = fmaf(bq.x - a.x, ax, a.x);
        bot = fmaf(dr.x - cl.x, ax, cl.x);
        wv[0] = fmaf(bot - top, ay, top);
        top = fmaf(bq.y - a.y, ax, a.y);
        bot = fmaf(dr.y - cl.y, ax, cl.y);
        wv[1] = fmaf(bot - top, ay, top);
        top = fmaf(bq.z - a.z, ax, a.z);
        bot = fmaf(dr.z - cl.z, ax, cl.z);
        wv[2] = fmaf(bot - top, ay, top);
        top = fmaf(bq.w - a.w, ax, a.w);
        bot = fmaf(dr.w - cl.w, ax, cl.w);
        wv[3] = fmaf(bot - top, ay, top);
      }
#pragma unroll
      for (int j = 0; j < 4; ++j) {
        const int c = 64 + c4 * 4 + j;
        const float vv = wv[j] * A.dw[c];
        const float* __restrict__ pwr = A.pw + (size_t)c * 64;
#pragma unroll
        for (int f = 0; f < 64; ++f) acc[f] = fmaf(vv, pwr[f], acc[f]);
      }
    }
  }

  // ---- store ----
  float4* __restrict__ o4 = (float4*)(A.out + (size_t)p * 64);
#pragma unroll
  for (int f4 = 0; f4 < 16; ++f4)
    o4[f4] = make_float4(acc[4 * f4], acc[4 * f4 + 1], acc[4 * f4 + 2], acc[4 * f4 + 3]);
}

extern "C" void kernel_launch(void* const* d_in, const int* in_sizes, int n_in,
                              void* d_out, int out_size, void* d_ws, size_t ws_size,
                              hipStream_t stream) {
  static const int HS[6] = {192, 96, 48, 24, 12, 6};
  static const int WS[6] = {384, 192, 96, 48, 24, 12};
  KArgs ka;
  int bstart = 0;
  size_t ooff = 0;
  for (int i = 0; i < 6; ++i) {
    ka.lv[i].xc   = (const float*)d_in[6 * i + 0];
    ka.lv[i].xp   = (const float*)d_in[6 * i + 1];
    ka.lv[i].fl   = (const float*)d_in[6 * i + 2];
    ka.lv[i].dw   = (const float*)d_in[6 * i + 3];
    ka.lv[i].pw   = (const float*)d_in[6 * i + 4];
    ka.lv[i].bias = (const float*)d_in[6 * i + 5];
    ka.lv[i].out  = (float*)d_out + ooff;
    const int npix = 4 * HS[i] * WS[i];
    ka.lv[i].H = HS[i];
    ka.lv[i].W = WS[i];
    ka.lv[i].npix = npix;
    ka.lv[i].block_start = bstart;
    bstart += (npix + 255) / 256;
    ooff += (size_t)npix * 64;
  }
  flowwarp_kernel<<<dim3(bstart), dim3(256), 0, stream>>>(ka);
}

// Round 2
// 478.736 us; speedup vs baseline: 1.2510x; 1.2510x over previous
//
#include <hip/hip_runtime.h>

// FlowWarp: 6 pyramid levels. Per level i:
//   warped = bilinear_warp(xp, +fl)   (dense_image_warp with flow=-fl)
//   x = concat([xc(64), warped(64), fl(2)])  -> 130 ch
//   out[f] = sum_c x[c]*dw[c]*pw[c][f] + bias[f]   (F=64)
//
// R2: burst line consumption. Each lane's data lives in 256B chunks (64ch*4B).
// Loads are issued in back-to-back bursts that fully consume whole 128B cache
// lines before FMA-ing, shrinking the line re-reference window from ~16 rolled
// iterations (~8K cyc, caused 3.8x HBM over-fetch in R1) to one burst.
// Also XCD-slab swizzle so next-row corner reuse hits the same XCD L2.

struct LevelArgs {
  const float* __restrict__ xc;
  const float* __restrict__ xp;
  const float* __restrict__ fl;
  const float* __restrict__ dw;
  const float* __restrict__ pw;
  const float* __restrict__ bias;
  float* __restrict__ out;
  int H, W, npix, block_start;
};

struct KArgs { LevelArgs lv[6]; int total_blocks; };

__global__ __launch_bounds__(256, 3) void flowwarp_kernel(KArgs ka) {
  // XCD swizzle: assume physical XCD = blockIdx % 8 (round-robin). Map so each
  // XCD gets a contiguous slab of logical blocks -> row-to-row xp reuse stays
  // in one XCD's 4MB L2.
  const int nb = ka.total_blocks;
  const int chunk = (nb + 7) >> 3;
  const int bp = (int)blockIdx.x;
  const int b = (bp & 7) * chunk + (bp >> 3);
  if (b >= nb) return;

  int Lr = 0;
#pragma unroll
  for (int i = 1; i < 6; ++i) Lr = (b >= ka.lv[i].block_start) ? i : Lr;
  const int L = __builtin_amdgcn_readfirstlane(Lr);  // wave-uniform level
  const LevelArgs A = ka.lv[L];

  const int p = (b - A.block_start) * 256 + (int)threadIdx.x;
  if (p >= A.npix) return;

  const int W = A.W, H = A.H;
  const int x = p % W;
  const int t = p / W;
  const int y = t % H;
  const int n = t / H;

  // ---- warp coordinates (tfa dense_image_warp with flow=-fl) ----
  const float fl0 = A.fl[2 * (size_t)p];
  const float fl1 = A.fl[2 * (size_t)p + 1];
  const float qy = (float)y + fl0;
  const float qx = (float)x + fl1;
  const float fy = fminf(fmaxf(floorf(qy), 0.0f), (float)(H - 2));
  const float fx = fminf(fmaxf(floorf(qx), 0.0f), (float)(W - 2));
  const int y0 = (int)fy, x0 = (int)fx;
  const float ay = fminf(fmaxf(qy - fy, 0.0f), 1.0f);
  const float ax = fminf(fmaxf(qx - fx, 0.0f), 1.0f);

  // ---- acc init: bias + flow channels (c=128,129) ----
  float acc[64];
  {
    const float s0 = fl0 * A.dw[128];
    const float s1 = fl1 * A.dw[129];
    const float* __restrict__ pr0 = A.pw + 128 * 64;
    const float* __restrict__ pr1 = A.pw + 129 * 64;
#pragma unroll
    for (int f = 0; f < 64; ++f)
      acc[f] = fmaf(s0, pr0[f], fmaf(s1, pr1[f], A.bias[f]));
  }

  // ---- xc channels c=0..63: 2 bursts of 8 float4 (one 128B line each) ----
  {
    const float4* __restrict__ xc4 = (const float4*)(A.xc + (size_t)p * 64);
#pragma unroll 1
    for (int h = 0; h < 2; ++h) {
      float4 r[8];
#pragma unroll
      for (int i = 0; i < 8; ++i) r[i] = xc4[h * 8 + i];
#pragma unroll
      for (int i = 0; i < 8; ++i) {
        const float vx[4] = {r[i].x, r[i].y, r[i].z, r[i].w};
#pragma unroll
        for (int j = 0; j < 4; ++j) {
          const int c = h * 32 + i * 4 + j;
          const float vv = vx[j] * A.dw[c];
          const float* __restrict__ pwr = A.pw + (size_t)c * 64;
#pragma unroll
          for (int f = 0; f < 64; ++f) acc[f] = fmaf(vv, pwr[f], acc[f]);
        }
      }
    }
  }

  // ---- warped channels c=64..127: 4 bursts of 16 float4 (4 corners x 64B) --
  {
    const float* __restrict__ base =
        A.xp + ((size_t)((n * H + y0) * W + x0)) * 64;
    const int W64 = W * 64;
    const float4* __restrict__ tl4 = (const float4*)base;
    const float4* __restrict__ tr4 = (const float4*)(base + 64);
    const float4* __restrict__ bl4 = (const float4*)(base + W64);
    const float4* __restrict__ br4 = (const float4*)(base + W64 + 64);
#pragma unroll 1
    for (int q = 0; q < 4; ++q) {
      float4 rtl[4], rtr[4], rbl[4], rbr[4];
#pragma unroll
      for (int i = 0; i < 4; ++i) {
        rtl[i] = tl4[q * 4 + i];
        rtr[i] = tr4[q * 4 + i];
        rbl[i] = bl4[q * 4 + i];
        rbr[i] = br4[q * 4 + i];
      }
#pragma unroll
      for (int i = 0; i < 4; ++i) {
        const float atl[4] = {rtl[i].x, rtl[i].y, rtl[i].z, rtl[i].w};
        const float atr[4] = {rtr[i].x, rtr[i].y, rtr[i].z, rtr[i].w};
        const float abl[4] = {rbl[i].x, rbl[i].y, rbl[i].z, rbl[i].w};
        const float abr[4] = {rbr[i].x, rbr[i].y, rbr[i].z, rbr[i].w};
#pragma unroll
        for (int j = 0; j < 4; ++j) {
          const float top = fmaf(atr[j] - atl[j], ax, atl[j]);
          const float bot = fmaf(abr[j] - abl[j], ax, abl[j]);
          const float wv = fmaf(bot - top, ay, top);
          const int c = 64 + q * 16 + i * 4 + j;
          const float vv = wv * A.dw[c];
          const float* __restrict__ pwr = A.pw + (size_t)c * 64;
#pragma unroll
          for (int f = 0; f < 64; ++f) acc[f] = fmaf(vv, pwr[f], acc[f]);
        }
      }
    }
  }

  // ---- store ----
  float4* __restrict__ o4 = (float4*)(A.out + (size_t)p * 64);
#pragma unroll
  for (int f4 = 0; f4 < 16; ++f4)
    o4[f4] = make_float4(acc[4 * f4], acc[4 * f4 + 1], acc[4 * f4 + 2],
                         acc[4 * f4 + 3]);
}

extern "C" void kernel_launch(void* const* d_in, const int* in_sizes, int n_in,
                              void* d_out, int out_size, void* d_ws, size_t ws_size,
                              hipStream_t stream) {
  static const int HS[6] = {192, 96, 48, 24, 12, 6};
  static const int WS[6] = {384, 192, 96, 48, 24, 12};
  KArgs ka;
  int bstart = 0;
  size_t ooff = 0;
  for (int i = 0; i < 6; ++i) {
    ka.lv[i].xc   = (const float*)d_in[6 * i + 0];
    ka.lv[i].xp   = (const float*)d_in[6 * i + 1];
    ka.lv[i].fl   = (const float*)d_in[6 * i + 2];
    ka.lv[i].dw   = (const float*)d_in[6 * i + 3];
    ka.lv[i].pw   = (const float*)d_in[6 * i + 4];
    ka.lv[i].bias = (const float*)d_in[6 * i + 5];
    ka.lv[i].out  = (float*)d_out + ooff;
    const int npix = 4 * HS[i] * WS[i];
    ka.lv[i].H = HS[i];
    ka.lv[i].W = WS[i];
    ka.lv[i].npix = npix;
    ka.lv[i].block_start = bstart;
    bstart += (npix + 255) / 256;
    ooff += (size_t)npix * 64;
  }
  ka.total_blocks = bstart;
  const int chunk = (bstart + 7) >> 3;
  flowwarp_kernel<<<dim3(chunk * 8), dim3(256), 0, stream>>>(ka);
}

// Round 3
// 403.272 us; speedup vs baseline: 1.4851x; 1.1871x over previous
//
#include <hip/hip_runtime.h>

// FlowWarp via MFMA. Per level:
//   warped = bilinear_warp(xp, +fl); x = [xc(64) | warped(64) | fl(2)] (130ch)
//   out[p][f] = sum_c x[c]*dw[c]*pw[c][f] + bias[f]
// R3: the per-pixel 130x64 matvec is GEMM-shaped -> bf16 MFMA 16x16x32.
//   prep kernel: W'[c][f] = dw[c]*pw[c][f] packed into B-fragment lane order
//   (bf16) in d_ws + fp32 epilogue tables (bias, fl-channel rows 128/129).
//   main kernel: phase1 burst-gather warped -> LDS bf16; phase2 per-wave
//   64pix x 64f tile, A-frags from global(xc)/LDS(warped), fl+bias exact fp32
//   in epilogue. Kills the R2 scalar-cache wall (pw rows via s_load broadcast
//   = 2B/cyc/wave demand stalled all waves; weights now sit in 64 VGPRs).

typedef __attribute__((ext_vector_type(8))) short bf16x8;
typedef __attribute__((ext_vector_type(4))) float f32x4;

#define WS_LVL_STRIDE 17408  // 16384 frag bytes + 768 table bytes, 256-align

__device__ inline unsigned rne_bf16_bits(float f) {
  unsigned u = __builtin_bit_cast(unsigned, f);
  u += 0x7fffu + ((u >> 16) & 1u);
  return u >> 16;
}
__device__ inline int pack_bf16x2(float a, float b) {
  return (int)(rne_bf16_bits(a) | (rne_bf16_bits(b) << 16));
}

struct LevelArgs {
  const float* __restrict__ xc;
  const float* __restrict__ xp;
  const float* __restrict__ fl;
  float* __restrict__ out;
  const char* __restrict__ wsl;  // frag[16KB] + tab[768B]
  int H, W, npix, block_start;
};
struct KArgs { LevelArgs lv[6]; int total_blocks; };

struct PrepLevel {
  const float* __restrict__ dw;
  const float* __restrict__ pw;
  const float* __restrict__ bias;
  char* __restrict__ wsl;
};
struct PrepArgs { PrepLevel lv[6]; };

// ---- prep: fold dw into pw, pack B-fragments (lane l holds B[k=(l>>4)*8+j][n=l&15]) ----
__global__ void prep_kernel(PrepArgs pa) {
  const PrepLevel P = pa.lv[blockIdx.x];
  int4* __restrict__ frag = (int4*)P.wsl;
  for (int e = (int)threadIdx.x; e < 1024; e += 256) {
    const int kt = e >> 8;            // k-tile 0..3 (k = kt*32 + ...)
    const int nt = (e >> 6) & 3;      // n-tile 0..3
    const int lane = e & 63;
    const int n = nt * 16 + (lane & 15);
    const int kb = kt * 32 + ((lane >> 4) & 3) * 8;
    int v[4];
#pragma unroll
    for (int jj = 0; jj < 4; ++jj) {
      const int k0 = kb + jj * 2;
      const float w0 = P.dw[k0] * P.pw[(size_t)k0 * 64 + n];
      const float w1 = P.dw[k0 + 1] * P.pw[(size_t)(k0 + 1) * 64 + n];
      v[jj] = pack_bf16x2(w0, w1);
    }
    frag[e] = make_int4(v[0], v[1], v[2], v[3]);
  }
  float* __restrict__ tab = (float*)(P.wsl + 16384);
  if (threadIdx.x < 64) {
    const int f = (int)threadIdx.x;
    tab[f] = P.bias[f];
    tab[64 + f] = P.dw[128] * P.pw[128 * 64 + f];
    tab[128 + f] = P.dw[129] * P.pw[129 * 64 + f];
  }
}

// LDS: 256 rows x 144B (64ch bf16 = 128B + 16B pad, keeps b128 alignment,
// balanced banks) + 256 x float2 fl stash
#define LDS_ROW 144
#define LDS_FL_OFF (256 * LDS_ROW)

__global__ __launch_bounds__(256, 3) void flowwarp_mfma(KArgs ka) {
  __shared__ __align__(16) char lds_raw[256 * LDS_ROW + 256 * 8];

  const int nb = ka.total_blocks;
  const int chunk = (nb + 7) >> 3;
  const int bp = (int)blockIdx.x;
  const int b = (bp & 7) * chunk + (bp >> 3);   // XCD-slab swizzle
  if (b >= nb) return;

  int Lr = 0;
#pragma unroll
  for (int i = 1; i < 6; ++i) Lr = (b >= ka.lv[i].block_start) ? i : Lr;
  const int L = __builtin_amdgcn_readfirstlane(Lr);
  const LevelArgs A = ka.lv[L];

  const int q = (int)threadIdx.x;
  const int p0 = (b - A.block_start) * 256;
  const int W = A.W, H = A.H;

  // ================= phase 1: bilinear gather -> LDS (bf16) =================
  {
    int p = p0 + q;
    if (p > A.npix - 1) p = A.npix - 1;   // tail blocks: clamp (rows unused)
    const int x = p % W;
    const int t = p / W;
    const int y = t % H;
    const int n = t / H;

    const float fl0 = A.fl[2 * (size_t)p];
    const float fl1 = A.fl[2 * (size_t)p + 1];
    ((float2*)(lds_raw + LDS_FL_OFF))[q] = make_float2(fl0, fl1);

    const float qy = (float)y + fl0;
    const float qx = (float)x + fl1;
    const float fy = fminf(fmaxf(floorf(qy), 0.0f), (float)(H - 2));
    const float fx = fminf(fmaxf(floorf(qx), 0.0f), (float)(W - 2));
    const int y0 = (int)fy, x0 = (int)fx;
    const float ay = fminf(fmaxf(qy - fy, 0.0f), 1.0f);
    const float ax = fminf(fmaxf(qx - fx, 0.0f), 1.0f);

    const float* __restrict__ base =
        A.xp + ((size_t)((n * H + y0) * W + x0)) * 64;
    const int W64 = W * 64;
    const float4* __restrict__ tl4 = (const float4*)base;
    const float4* __restrict__ tr4 = (const float4*)(base + 64);
    const float4* __restrict__ bl4 = (const float4*)(base + W64);
    const float4* __restrict__ br4 = (const float4*)(base + W64 + 64);
    int4* __restrict__ xrow = (int4*)(lds_raw + (size_t)q * LDS_ROW);

#pragma unroll 1
    for (int bq = 0; bq < 4; ++bq) {   // 4 bursts x 16 ch: full-line consume
      float4 rtl[4], rtr[4], rbl[4], rbr[4];
#pragma unroll
      for (int i = 0; i < 4; ++i) {
        rtl[i] = tl4[bq * 4 + i];
        rtr[i] = tr4[bq * 4 + i];
        rbl[i] = bl4[bq * 4 + i];
        rbr[i] = br4[bq * 4 + i];
      }
      int v[8];
#pragma unroll
      for (int i = 0; i < 4; ++i) {
        const float atl[4] = {rtl[i].x, rtl[i].y, rtl[i].z, rtl[i].w};
        const float atr[4] = {rtr[i].x, rtr[i].y, rtr[i].z, rtr[i].w};
        const float abl[4] = {rbl[i].x, rbl[i].y, rbl[i].z, rbl[i].w};
        const float abr[4] = {rbr[i].x, rbr[i].y, rbr[i].z, rbr[i].w};
        float wv[4];
#pragma unroll
        for (int j = 0; j < 4; ++j) {
          const float top = fmaf(atr[j] - atl[j], ax, atl[j]);
          const float bot = fmaf(abr[j] - abl[j], ax, abl[j]);
          wv[j] = fmaf(bot - top, ay, top);
        }
        v[i * 2] = pack_bf16x2(wv[0], wv[1]);
        v[i * 2 + 1] = pack_bf16x2(wv[2], wv[3]);
      }
      xrow[bq * 2] = make_int4(v[0], v[1], v[2], v[3]);
      xrow[bq * 2 + 1] = make_int4(v[4], v[5], v[6], v[7]);
    }
  }
  __syncthreads();

  // ================= phase 2: MFMA 64pix x 64f per wave =================
  const int lane = q & 63;
  const int w = q >> 6;
  const int m16 = lane & 15;
  const int q4l = lane >> 4;

  // B-fragments: 4 ktiles x 4 ntiles, 16B/lane each, resident in VGPRs
  const int4* __restrict__ bfr = (const int4*)A.wsl;
  bf16x8 Bf[4][4];
#pragma unroll
  for (int kt = 0; kt < 4; ++kt)
#pragma unroll
    for (int nt = 0; nt < 4; ++nt)
      Bf[kt][nt] = __builtin_bit_cast(bf16x8, bfr[(kt * 4 + nt) * 64 + lane]);

  const float* __restrict__ tab = (const float*)(A.wsl + 16384);
  float bv[4], t0v[4], t1v[4];
#pragma unroll
  for (int nt = 0; nt < 4; ++nt) {
    const int col = nt * 16 + m16;
    bv[nt] = tab[col];
    t0v[nt] = tab[64 + col];
    t1v[nt] = tab[128 + col];
  }
  const float2* __restrict__ flsh = (const float2*)(lds_raw + LDS_FL_OFF);

#pragma unroll 1
  for (int mt = 0; mt < 4; ++mt) {
    const int lrow = w * 64 + mt * 16;
    // A-frags, xc (k-tiles 0,1) straight from global with cvt
    int pm = p0 + lrow + m16;
    if (pm > A.npix - 1) pm = A.npix - 1;
    const float* __restrict__ xcp = A.xc + (size_t)pm * 64 + q4l * 8;
    const float4 a0 = *(const float4*)xcp;
    const float4 a1 = *(const float4*)(xcp + 4);
    const float4 a2 = *(const float4*)(xcp + 32);
    const float4 a3 = *(const float4*)(xcp + 36);
    int av[8];
    av[0] = pack_bf16x2(a0.x, a0.y); av[1] = pack_bf16x2(a0.z, a0.w);
    av[2] = pack_bf16x2(a1.x, a1.y); av[3] = pack_bf16x2(a1.z, a1.w);
    av[4] = pack_bf16x2(a2.x, a2.y); av[5] = pack_bf16x2(a2.z, a2.w);
    av[6] = pack_bf16x2(a3.x, a3.y); av[7] = pack_bf16x2(a3.z, a3.w);
    const bf16x8 A0 = __builtin_bit_cast(bf16x8, make_int4(av[0], av[1], av[2], av[3]));
    const bf16x8 A1 = __builtin_bit_cast(bf16x8, make_int4(av[4], av[5], av[6], av[7]));
    // A-frags, warped (k-tiles 2,3) from LDS
    const int4* __restrict__ lrp =
        (const int4*)(lds_raw + (size_t)(lrow + m16) * LDS_ROW + q4l * 16);
    const bf16x8 A2 = __builtin_bit_cast(bf16x8, lrp[0]);
    const bf16x8 A3 = __builtin_bit_cast(bf16x8, lrp[4]);  // +64B

    f32x4 acc[4] = {{0.f, 0.f, 0.f, 0.f}, {0.f, 0.f, 0.f, 0.f},
                    {0.f, 0.f, 0.f, 0.f}, {0.f, 0.f, 0.f, 0.f}};
#pragma unroll
    for (int nt = 0; nt < 4; ++nt) {
      acc[nt] = __builtin_amdgcn_mfma_f32_16x16x32_bf16(A0, Bf[0][nt], acc[nt], 0, 0, 0);
      acc[nt] = __builtin_amdgcn_mfma_f32_16x16x32_bf16(A1, Bf[1][nt], acc[nt], 0, 0, 0);
      acc[nt] = __builtin_amdgcn_mfma_f32_16x16x32_bf16(A2, Bf[2][nt], acc[nt], 0, 0, 0);
      acc[nt] = __builtin_amdgcn_mfma_f32_16x16x32_bf16(A3, Bf[3][nt], acc[nt], 0, 0, 0);
    }

    // epilogue: D row r=(lane>>4)*4+i, col=lane&15 (per n-tile). fl terms exact fp32.
    float f0[4], f1[4];
#pragma unroll
    for (int i = 0; i < 4; ++i) {
      const float2 f = flsh[lrow + q4l * 4 + i];
      f0[i] = f.x; f1[i] = f.y;
    }
#pragma unroll
    for (int i = 0; i < 4; ++i) {
      const int prow = p0 + lrow + q4l * 4 + i;
      if (prow < A.npix) {
        float* __restrict__ orow = A.out + (size_t)prow * 64 + m16;
#pragma unroll
        for (int nt = 0; nt < 4; ++nt)
          orow[nt * 16] = acc[nt][i] + bv[nt] + f0[i] * t0v[nt] + f1[i] * t1v[nt];
      }
    }
  }
}

extern "C" void kernel_launch(void* const* d_in, const int* in_sizes, int n_in,
                              void* d_out, int out_size, void* d_ws, size_t ws_size,
                              hipStream_t stream) {
  static const int HS[6] = {192, 96, 48, 24, 12, 6};
  static const int WS[6] = {384, 192, 96, 48, 24, 12};
  PrepArgs pa;
  KArgs ka;
  int bstart = 0;
  size_t ooff = 0;
  for (int i = 0; i < 6; ++i) {
    char* wsl = (char*)d_ws + (size_t)i * WS_LVL_STRIDE;
    pa.lv[i].dw   = (const float*)d_in[6 * i + 3];
    pa.lv[i].pw   = (const float*)d_in[6 * i + 4];
    pa.lv[i].bias = (const float*)d_in[6 * i + 5];
    pa.lv[i].wsl  = wsl;
    ka.lv[i].xc  = (const float*)d_in[6 * i + 0];
    ka.lv[i].xp  = (const float*)d_in[6 * i + 1];
    ka.lv[i].fl  = (const float*)d_in[6 * i + 2];
    ka.lv[i].out = (float*)d_out + ooff;
    ka.lv[i].wsl = wsl;
    const int npix = 4 * HS[i] * WS[i];
    ka.lv[i].H = HS[i];
    ka.lv[i].W = WS[i];
    ka.lv[i].npix = npix;
    ka.lv[i].block_start = bstart;
    bstart += (npix + 255) / 256;
    ooff += (size_t)npix * 64;
  }
  ka.total_blocks = bstart;
  prep_kernel<<<dim3(6), dim3(256), 0, stream>>>(pa);
  const int chunk = (bstart + 7) >> 3;
  flowwarp_mfma<<<dim3(chunk * 8), dim3(256), 0, stream>>>(ka);
}